// Round 6
// baseline (278.178 us; speedup 1.0000x reference)
//
#include <hip/hip_runtime.h>
#include <hip/hip_bf16.h>

#define NN 50000
#define EE 800000
#define GG 1024
#define NB 196            // (NN+255)/256 scan blocks
#define PE (EE + 4 * NN)  // padded edge-slot capacity (row pad < 4 each)
#define DUMMY 65535       // pad source row (zeros)

// ---- bf16x2 helpers (packed uint: lo16 = even feature, hi16 = odd)
__device__ __forceinline__ float blo(unsigned u) { return __uint_as_float(u << 16); }
__device__ __forceinline__ float bhi(unsigned u) { return __uint_as_float(u & 0xffff0000u); }
__device__ __forceinline__ unsigned packbf(float a, float b) {
    unsigned ua = __float_as_uint(a); ua += 0x7fffu + ((ua >> 16) & 1u);
    unsigned ub = __float_as_uint(b); ub += 0x7fffu + ((ub >> 16) & 1u);
    return (ua >> 16) | (ub & 0xffff0000u);
}

// ---------------------------------------------------------------- dst histogram
__global__ __launch_bounds__(256) void k_count(const int* __restrict__ dst,
                                               int* __restrict__ cnt) {
    int i = blockIdx.x * 256 + threadIdx.x;
    if (i < EE) atomicAdd(&cnt[dst[i]], 1);
}

// ---------------------------------------------------------------- scan level 1 (over padded counts)
__global__ __launch_bounds__(256) void k_scan1(const int* __restrict__ cnt,
                                               int* __restrict__ rowptr,
                                               int* __restrict__ part,
                                               float* __restrict__ dinv) {
    __shared__ int sh[256];
    int t = threadIdx.x;
    int i = blockIdx.x * 256 + t;
    int v  = (i < NN) ? cnt[i] : 0;
    int pv = (v + 3) & ~3;                 // pad each row to multiple of 4
    if (i < NN) dinv[i] = rsqrtf((float)v + 1.0f);
    sh[t] = pv;
    __syncthreads();
    int acc = pv;
    for (int off = 1; off < 256; off <<= 1) {
        int add = (t >= off) ? sh[t - off] : 0;
        __syncthreads();
        acc += add;
        sh[t] = acc;
        __syncthreads();
    }
    if (i < NN) rowptr[i] = acc - pv;
    if (t == 255) part[blockIdx.x] = acc;
}

// ---------------------------------------------------------------- scan level 2
__global__ __launch_bounds__(256) void k_scan2(int* __restrict__ part,
                                               int* __restrict__ partoff,
                                               int* __restrict__ rowptr) {
    __shared__ int sh[256];
    int t = threadIdx.x;
    int v = (t < NB) ? part[t] : 0;
    sh[t] = v;
    __syncthreads();
    int acc = v;
    for (int off = 1; off < 256; off <<= 1) {
        int add = (t >= off) ? sh[t - off] : 0;
        __syncthreads();
        acc += add;
        sh[t] = acc;
        __syncthreads();
    }
    if (t < NB) partoff[t] = acc - v;
    if (t == 255) rowptr[NN] = acc;
}

// ---------------------------------------------------------------- scan level 3
__global__ __launch_bounds__(256) void k_scan3(int* __restrict__ rowptr,
                                               const int* __restrict__ partoff) {
    int i = blockIdx.x * 256 + threadIdx.x;
    if (i < NN) rowptr[i] += partoff[blockIdx.x];
}

// ---------------------------------------------------------------- fill CSR (ushort sources)
__global__ __launch_bounds__(256) void k_fill(const int* __restrict__ src,
                                              const int* __restrict__ dst,
                                              const int* __restrict__ rowptr,
                                              int* __restrict__ cnt,
                                              unsigned short* __restrict__ csr16) {
    int e = blockIdx.x * 256 + threadIdx.x;
    if (e < EE) {
        int d = dst[e];
        int slot = atomicSub(&cnt[d], 1) - 1;
        csr16[rowptr[d] + slot] = (unsigned short)src[e];
    }
}

// ---------------------------------------------------------------- GEMM 64x64, scaled by dinv[row], bf16 out
template <bool BF16IN>
__global__ __launch_bounds__(256) void k_gemm(const void* __restrict__ hv,
                                              const float* __restrict__ W,
                                              const float* __restrict__ dinv,
                                              unsigned* __restrict__ hWs, int n) {
    __shared__ float Wl[64 * 64];   // as float4 [64][16]
    __shared__ float hl[64 * 65];   // padded stride 65
    int tid  = threadIdx.x;
    int base = blockIdx.x * 64;

    const float4* Wg4 = (const float4*)W;
    float4* Wl4 = (float4*)Wl;
#pragma unroll
    for (int i = 0; i < 4; ++i) Wl4[tid + i * 256] = Wg4[tid + i * 256];

    if (BF16IN) {
        const unsigned* hb = (const unsigned*)hv;
#pragma unroll
        for (int i = 0; i < 8; ++i) {
            int idx = tid + i * 256;        // uint index in 64x32 tile
            int row = idx >> 5;
            int pc  = idx & 31;
            unsigned v = (base + row < n) ? hb[(size_t)(base + row) * 32 + pc] : 0u;
            hl[row * 65 + 2 * pc]     = blo(v);
            hl[row * 65 + 2 * pc + 1] = bhi(v);
        }
    } else {
        const float4* hg = (const float4*)hv;
#pragma unroll
        for (int i = 0; i < 4; ++i) {
            int idx4 = tid + i * 256;
            int row  = idx4 >> 4;
            int c4   = idx4 & 15;
            float4 v = make_float4(0.f, 0.f, 0.f, 0.f);
            if (base + row < n) v = hg[(size_t)(base + row) * 16 + c4];
            float* dp = &hl[row * 65 + c4 * 4];
            dp[0] = v.x; dp[1] = v.y; dp[2] = v.z; dp[3] = v.w;
        }
    }
    __syncthreads();

    int col4 = tid & 15;
    int rp   = tid >> 4;
    float4 a0 = make_float4(0, 0, 0, 0), a1 = a0, a2 = a0, a3 = a0;
    const float4* WlF4 = (const float4*)Wl;
#pragma unroll 8
    for (int k = 0; k < 64; ++k) {
        float4 w = WlF4[k * 16 + col4];
        float h0 = hl[rp * 65 + k];
        float h1 = hl[(rp + 16) * 65 + k];
        float h2 = hl[(rp + 32) * 65 + k];
        float h3 = hl[(rp + 48) * 65 + k];
        a0.x = fmaf(h0, w.x, a0.x); a0.y = fmaf(h0, w.y, a0.y); a0.z = fmaf(h0, w.z, a0.z); a0.w = fmaf(h0, w.w, a0.w);
        a1.x = fmaf(h1, w.x, a1.x); a1.y = fmaf(h1, w.y, a1.y); a1.z = fmaf(h1, w.z, a1.z); a1.w = fmaf(h1, w.w, a1.w);
        a2.x = fmaf(h2, w.x, a2.x); a2.y = fmaf(h2, w.y, a2.y); a2.z = fmaf(h2, w.z, a2.z); a2.w = fmaf(h2, w.w, a2.w);
        a3.x = fmaf(h3, w.x, a3.x); a3.y = fmaf(h3, w.y, a3.y); a3.z = fmaf(h3, w.z, a3.z); a3.w = fmaf(h3, w.w, a3.w);
    }
    float4 accs[4] = {a0, a1, a2, a3};
#pragma unroll
    for (int r = 0; r < 4; ++r) {
        int row = base + rp + 16 * r;
        if (row < n) {
            float s = dinv[row];
            ((uint2*)hWs)[(size_t)row * 16 + col4] =
                make_uint2(packbf(accs[r].x * s, accs[r].y * s),
                           packbf(accs[r].z * s, accs[r].w * s));
        }
    }
}

// ---------------------------------------------------------------- gather conv: one wave per node
// 16 lanes per edge: q = lane>>4 (edge slot within 4-chunk), f = lane&15 (feature quad)
// one 64-lane load = 4 edges x 128B. rows padded to x4 with DUMMY (zero row).
template <bool POOL>
__global__ __launch_bounds__(256) void k_gather(const int* __restrict__ rowptr,
                                                const unsigned short* __restrict__ csr16,
                                                const unsigned* __restrict__ hWs,
                                                const float* __restrict__ dinv,
                                                const float* __restrict__ bias,
                                                unsigned* __restrict__ out,
                                                const int* __restrict__ batch,
                                                float* __restrict__ g) {
    int gt   = blockIdx.x * 256 + threadIdx.x;
    int i    = gt >> 6;          // node (one wave)
    int lane = gt & 63;
    int q    = lane >> 4;        // edge slot 0..3
    int f    = lane & 15;        // feature quad (features 4f..4f+3)
    if (i >= NN) return;

    const uint2* hw2 = (const uint2*)hWs;   // row = 16 uint2

    float a0 = 0.f, a1 = 0.f, a2 = 0.f, a3 = 0.f;
    if (q == 0) {                // self term on quarter 0
        uint2 s = hw2[(size_t)i * 16 + f];
        a0 = blo(s.x); a1 = bhi(s.x); a2 = blo(s.y); a3 = bhi(s.y);
    }

    int e  = rowptr[i];
    int e1 = rowptr[i + 1];      // multiple-of-4 row length
    for (; e + 16 <= e1; e += 16) {
        int i0 = csr16[e + q];
        int i1 = csr16[e + 4 + q];
        int i2 = csr16[e + 8 + q];
        int i3 = csr16[e + 12 + q];
        uint2 v0 = hw2[(size_t)i0 * 16 + f];
        uint2 v1 = hw2[(size_t)i1 * 16 + f];
        uint2 v2 = hw2[(size_t)i2 * 16 + f];
        uint2 v3 = hw2[(size_t)i3 * 16 + f];
        a0 += (blo(v0.x) + blo(v1.x)) + (blo(v2.x) + blo(v3.x));
        a1 += (bhi(v0.x) + bhi(v1.x)) + (bhi(v2.x) + bhi(v3.x));
        a2 += (blo(v0.y) + blo(v1.y)) + (blo(v2.y) + blo(v3.y));
        a3 += (bhi(v0.y) + bhi(v1.y)) + (bhi(v2.y) + bhi(v3.y));
    }
    for (; e < e1; e += 4) {
        int ii = csr16[e + q];
        uint2 v = hw2[(size_t)ii * 16 + f];
        a0 += blo(v.x); a1 += bhi(v.x); a2 += blo(v.y); a3 += bhi(v.y);
    }

    // reduce across the 4 quarters (lanes f, f+16, f+32, f+48)
    a0 += __shfl_xor(a0, 16); a0 += __shfl_xor(a0, 32);
    a1 += __shfl_xor(a1, 16); a1 += __shfl_xor(a1, 32);
    a2 += __shfl_xor(a2, 16); a2 += __shfl_xor(a2, 32);
    a3 += __shfl_xor(a3, 16); a3 += __shfl_xor(a3, 32);

    if (q == 0) {
        float d  = dinv[i];
        float4 bb = ((const float4*)bias)[f];
        float o0 = fmaxf(fmaf(d, a0, bb.x), 0.f);
        float o1 = fmaxf(fmaf(d, a1, bb.y), 0.f);
        float o2 = fmaxf(fmaf(d, a2, bb.z), 0.f);
        float o3 = fmaxf(fmaf(d, a3, bb.w), 0.f);
        if (POOL) {
            int bg = batch[i];
            float* gp = &g[(size_t)bg * 64 + 4 * f];
            unsafeAtomicAdd(gp,     o0);
            unsafeAtomicAdd(gp + 1, o1);
            unsafeAtomicAdd(gp + 2, o2);
            unsafeAtomicAdd(gp + 3, o3);
        } else {
            ((uint2*)out)[(size_t)i * 16 + f] = make_uint2(packbf(o0, o1), packbf(o2, o3));
        }
    }
}

// ---------------------------------------------------------------- dense head, one block per graph
__global__ __launch_bounds__(256) void k_dense(const float* __restrict__ g,
                                               const float* __restrict__ Wd1, const float* __restrict__ bd1,
                                               const float* __restrict__ Wd2, const float* __restrict__ bd2,
                                               const float* __restrict__ Wa,  const float* __restrict__ ba,
                                               const float* __restrict__ temp,
                                               const float* __restrict__ mean,
                                               const float* __restrict__ stdv,
                                               float* __restrict__ out) {
    __shared__ float gl[64];
    __shared__ float d1[256];
    __shared__ float d2[128];
    __shared__ float coef[3];
    int tid = threadIdx.x;
    int gid = blockIdx.x;

    if (tid < 64) gl[tid] = fmaxf(g[(size_t)gid * 64 + tid], 0.f);
    __syncthreads();

    float a = bd1[tid];
#pragma unroll 8
    for (int k = 0; k < 64; ++k) a = fmaf(gl[k], Wd1[k * 256 + tid], a);
    d1[tid] = fmaxf(a, 0.f);
    __syncthreads();

    if (tid < 128) {
        float a2 = bd2[tid];
#pragma unroll 8
        for (int k = 0; k < 256; ++k) a2 = fmaf(d1[k], Wd2[k * 128 + tid], a2);
        d2[tid] = fmaxf(a2, 0.f);
    }
    __syncthreads();

    if (tid < 3) {
        float c = ba[tid];
        for (int k = 0; k < 128; ++k) c = fmaf(d2[k], Wa[k * 3 + tid], c);
        coef[tid] = c;
    }
    __syncthreads();

    if (tid == 0) {
        float A = coef[0], B = coef[1], C = coef[2];
        float T = temp[gid];
        float logP = A - B / (T + C);
        out[gid] = (logP - mean[0]) / stdv[0];
    }
}

// ----------------------------------------------------------------
extern "C" void kernel_launch(void* const* d_in, const int* in_sizes, int n_in,
                              void* d_out, int out_size, void* d_ws, size_t ws_size,
                              hipStream_t stream) {
    (void)in_sizes; (void)n_in; (void)out_size; (void)ws_size;
    const float* x     = (const float*)d_in[0];
    const int*   edges = (const int*)d_in[1];
    const int*   batch = (const int*)d_in[2];
    const float* temp  = (const float*)d_in[3];
    const float* mean  = (const float*)d_in[4];
    const float* stdv  = (const float*)d_in[5];
    const float* Wg1 = (const float*)d_in[6];  const float* bg1 = (const float*)d_in[7];
    const float* Wg2 = (const float*)d_in[8];  const float* bg2 = (const float*)d_in[9];
    const float* Wg3 = (const float*)d_in[10]; const float* bg3 = (const float*)d_in[11];
    const float* Wd1 = (const float*)d_in[12]; const float* bd1 = (const float*)d_in[13];
    const float* Wd2 = (const float*)d_in[14]; const float* bd2 = (const float*)d_in[15];
    const float* Wa  = (const float*)d_in[16]; const float* ba  = (const float*)d_in[17];

    // ---- workspace layout (8-B aligned first)
    char* wsb = (char*)d_ws;
    unsigned* bufB = (unsigned*)wsb;                       // 65536*32 u32 (gathered hWs; row DUMMY = zeros)
    unsigned* bufA = bufB + (size_t)65536 * 32;            // NN*32 u32
    float*    gbuf = (float*)(bufA + (size_t)NN * 32);     // GG*64
    float*    dinv = gbuf + (size_t)GG * 64;               // NN
    int*      cnt     = (int*)(dinv + NN);                 // NN
    int*      rowptr  = cnt + NN;                          // NN+1
    int*      part    = rowptr + NN + 1;                   // NB
    int*      partoff = part + NB;                         // NB
    unsigned short* csr16 = (unsigned short*)(partoff + NB);  // PE

    const int* srcIdx = edges;
    const int* dstIdx = edges + EE;

    // ---- CSR build
    hipMemsetAsync(cnt, 0, NN * sizeof(int), stream);
    hipMemsetAsync(csr16, 0xFF, (size_t)PE * sizeof(unsigned short), stream);  // pad slots -> DUMMY
    hipMemsetAsync(bufB + (size_t)DUMMY * 32, 0, 128, stream);                 // zero dummy row
    hipMemsetAsync(gbuf, 0, (size_t)GG * 64 * sizeof(float), stream);
    k_count<<<(EE + 255) / 256, 256, 0, stream>>>(dstIdx, cnt);
    k_scan1<<<NB, 256, 0, stream>>>(cnt, rowptr, part, dinv);
    k_scan2<<<1, 256, 0, stream>>>(part, partoff, rowptr);
    k_scan3<<<NB, 256, 0, stream>>>(rowptr, partoff);
    k_fill<<<(EE + 255) / 256, 256, 0, stream>>>(srcIdx, dstIdx, rowptr, cnt, csr16);

    const int GEMM_BLOCKS = (NN + 63) / 64;
    const int GATH_BLOCKS = (NN * 64 + 255) / 256;

    // ---- layer 1: x(fp32) -> bufB(hWs bf16) -> bufA(bf16)
    k_gemm<false><<<GEMM_BLOCKS, 256, 0, stream>>>(x, Wg1, dinv, bufB, NN);
    k_gather<false><<<GATH_BLOCKS, 256, 0, stream>>>(rowptr, csr16, bufB, dinv, bg1, bufA, batch, gbuf);

    // ---- layer 2: bufA -> bufB -> bufA
    k_gemm<true><<<GEMM_BLOCKS, 256, 0, stream>>>(bufA, Wg2, dinv, bufB, NN);
    k_gather<false><<<GATH_BLOCKS, 256, 0, stream>>>(rowptr, csr16, bufB, dinv, bg2, bufA, batch, gbuf);

    // ---- layer 3: bufA -> bufB -> pool into gbuf (no feature write)
    k_gemm<true><<<GEMM_BLOCKS, 256, 0, stream>>>(bufA, Wg3, dinv, bufB, NN);
    k_gather<true><<<GATH_BLOCKS, 256, 0, stream>>>(rowptr, csr16, bufB, dinv, bg3, bufA, batch, gbuf);

    // ---- head
    k_dense<<<GG, 256, 0, stream>>>(gbuf, Wd1, bd1, Wd2, bd2, Wa, ba, temp, mean, stdv, (float*)d_out);
}